// Round 9
// baseline (273.932 us; speedup 1.0000x reference)
//
#include <hip/hip_runtime.h>
#include <math.h>

#define B_   4096
#define HB   16      // samples per head block

typedef __attribute__((ext_vector_type(8)))  short bf16x8;   // 8 bf16 = 4 VGPR
typedef __attribute__((ext_vector_type(4)))  float f32x4;
typedef __attribute__((ext_vector_type(16))) float f32x16;

// packed f32->bf16 RNE, single VALU instruction (gfx950; no builtin — T12 recipe)
__device__ __forceinline__ unsigned int pk2(float a, float b) {
    unsigned int r;
    asm("v_cvt_pk_bf16_f32 %0, %1, %2" : "=v"(r) : "v"(a), "v"(b));
    return r;
}
__device__ __forceinline__ f32x16 zero16() {
    f32x16 z;
    #pragma unroll
    for (int i = 0; i < 16; ++i) z[i] = 0.f;
    return z;
}
__device__ __forceinline__ float max4(float a, float b, float c, float d) {
    return fmaxf(fmaxf(a, b), fmaxf(c, d));
}
// quad (lanes t=0..3) all-reduce max / sum via DPP
__device__ __forceinline__ float maxq(float v) {
    int y1 = __builtin_amdgcn_update_dpp(0, __float_as_int(v), 0xB1, 0xF, 0xF, true);
    float v1 = fmaxf(v, __int_as_float(y1));
    int y2 = __builtin_amdgcn_update_dpp(0, __float_as_int(v1), 0x4E, 0xF, 0xF, true);
    return fmaxf(v1, __int_as_float(y2));
}
__device__ __forceinline__ float sumq(float v) {
    int y1 = __builtin_amdgcn_update_dpp(0, __float_as_int(v), 0xB1, 0xF, 0xF, true);
    float v1 = v + __int_as_float(y1);
    int y2 = __builtin_amdgcn_update_dpp(0, __float_as_int(v1), 0x4E, 0xF, 0xF, true);
    return v1 + __int_as_float(y2);
}

// ---------------------------------------------------------------------------
// prep: all MFMA fragments (56 x 64 lanes x 16B). A and B fragment lane
// layouts are identical on gfx950 (16x16x32: n=lane&15, k=(lane>>4)*8+j).
//  e 0..19 : phys phase-2 (16x16x32), e=(kk*2+Ks)*2+ftile
//  e 20..23: encoder conv (32x32x16), e-20=enc*2+mt; j<9 W, j==15 bias
//  e 24..25: phys phase-1 (32x32x16), mt=e-24;       j<15 W, j==15 bias
//  e 26..41: head stage-A [Ws|Wd] concat, K=64 N=64(o<60 valid):
//            e = 26 + side*8 + Kc*4 + ntile   (side 0=v, 1=p)
//  e 42..43: head Wsp, K=32 (k<30 W, k31 bsp), N=32 (o<30): e = 42+ntile
//  e 44..55: head Wa,  K=32 (k<30 W, k31 ba),  N=192:       e = 44+ntile
// ---------------------------------------------------------------------------
__global__ void prep_frags(const float* __restrict__ W2,
                           const float* __restrict__ Wc_v,
                           const float* __restrict__ Wc_p,
                           const float* __restrict__ W1,
                           const float* __restrict__ bc_v,
                           const float* __restrict__ bc_p,
                           const float* __restrict__ b1,
                           const float* __restrict__ Ws_v,
                           const float* __restrict__ Wd_v,
                           const float* __restrict__ Ws_p,
                           const float* __restrict__ Wd_p,
                           const float* __restrict__ Wsp,
                           const float* __restrict__ bsp,
                           const float* __restrict__ Wa,
                           const float* __restrict__ ba,
                           unsigned short* __restrict__ ws_frag)
{
    int gid = blockIdx.x * 256 + threadIdx.x;
    if (gid >= 56 * 64) return;
    int lane = gid & 63, e = gid >> 6;
    unsigned int w[4];
    if (e < 20) {
        int ft = e & 1, Ks = (e >> 1) & 1, kk = e >> 2;
        int m = lane & 15, kg = lane >> 4;
        int f = ft * 16 + m;
        #pragma unroll
        for (int p = 0; p < 4; ++p) {
            int i0 = Ks * 32 + kg * 8 + 2 * p;
            float v0 = (f < 30) ? W2[f * 320 + i0 * 5 + kk] : 0.f;
            float v1 = (f < 30) ? W2[f * 320 + (i0 + 1) * 5 + kk] : 0.f;
            w[p] = pk2(v0, v1);
        }
    } else if (e < 24) {
        int e2 = e - 20, enc = e2 >> 1, mt = e2 & 1;
        const float* Wc = enc ? Wc_p : Wc_v;
        const float* bc = enc ? bc_p : bc_v;
        int c = mt * 32 + (lane & 31), kg = lane >> 5;
        #pragma unroll
        for (int p = 0; p < 4; ++p) {
            int j0 = kg * 8 + 2 * p, j1 = j0 + 1;
            float v0 = (j0 < 9) ? Wc[c * 9 + (j0 % 3) * 3 + (j0 / 3)] : 0.f;
            float v1 = (j1 < 9) ? Wc[c * 9 + (j1 % 3) * 3 + (j1 / 3)]
                                : (j1 == 15 ? bc[c] : 0.f);
            w[p] = pk2(v0, v1);
        }
    } else if (e < 26) {
        int mt = e - 24;
        int c = mt * 32 + (lane & 31), kg = lane >> 5;
        #pragma unroll
        for (int p = 0; p < 4; ++p) {
            int j0 = kg * 8 + 2 * p, j1 = j0 + 1;
            float v0 = (j0 < 15) ? W1[c * 15 + (j0 % 3) * 5 + (j0 / 3)] : 0.f;
            float v1 = (j1 < 15) ? W1[c * 15 + (j1 % 3) * 5 + (j1 / 3)]
                                 : (j1 == 15 ? b1[c] : 0.f);
            w[p] = pk2(v0, v1);
        }
    } else if (e < 42) {
        int e2 = e - 26;
        int side = e2 >> 3, idx = e2 & 7;
        int Kc = idx >> 2, nt = idx & 3;
        const float* Ws = side ? Ws_p : Ws_v;
        const float* Wd = side ? Wd_p : Wd_v;
        int o = nt * 16 + (lane & 15), kg = lane >> 4;
        #pragma unroll
        for (int p = 0; p < 4; ++p) {
            int j0 = Kc * 32 + kg * 8 + 2 * p, j1 = j0 + 1;
            float v0 = (o < 30) ? Ws[j0 * 30 + o] : (o < 60 ? Wd[j0 * 30 + o - 30] : 0.f);
            float v1 = (o < 30) ? Ws[j1 * 30 + o] : (o < 60 ? Wd[j1 * 30 + o - 30] : 0.f);
            w[p] = pk2(v0, v1);
        }
    } else if (e < 44) {
        int nt = e - 42;
        int o = nt * 16 + (lane & 15), kg = lane >> 4;
        #pragma unroll
        for (int p = 0; p < 4; ++p) {
            int j0 = kg * 8 + 2 * p, j1 = j0 + 1;
            float v0 = 0.f, v1 = 0.f;
            if (o < 30) {
                v0 = (j0 < 30) ? Wsp[j0 * 30 + o] : (j0 == 31 ? bsp[o] : 0.f);
                v1 = (j1 < 30) ? Wsp[j1 * 30 + o] : (j1 == 31 ? bsp[o] : 0.f);
            }
            w[p] = pk2(v0, v1);
        }
    } else {
        int nt = e - 44;
        int c = nt * 16 + (lane & 15), kg = lane >> 4;
        #pragma unroll
        for (int p = 0; p < 4; ++p) {
            int j0 = kg * 8 + 2 * p, j1 = j0 + 1;
            float v0 = (j0 < 30) ? Wa[j0 * 192 + c] : (j0 == 31 ? ba[c] : 0.f);
            float v1 = (j1 < 30) ? Wa[j1 * 192 + c] : (j1 == 31 ? ba[c] : 0.f);
            w[p] = pk2(v0, v1);
        }
    }
    ((uint4*)ws_frag)[gid] = make_uint4(w[0], w[1], w[2], w[3]);
}

// ---------------------------------------------------------------------------
// MERGED encode + phys. grid = 3*B_, type = bx%3 (0: enc S_V, 1: enc S_P,
// 2: phys S_P1). R9: REVERT to R7-verified epilogues (R8's abs/ones-MFMA
// NaN'd — suspected in-place VALU overwrite of an in-flight MFMA operand);
// only change vs R7 is `#pragma unroll 2` on the two staging loops so the
// compiler overlaps iter i+1's ds_read/pk2 under iter i's accumulate chain.
// ---------------------------------------------------------------------------
#define P1TS 72
__global__ __launch_bounds__(512, 4) void enc_phys_kernel(
    const float* __restrict__ S_V, const float* __restrict__ S_P,
    const float* __restrict__ S_P1,
    const unsigned short* __restrict__ Frag,
    const float* __restrict__ b2,
    float* __restrict__ hv, float* __restrict__ hp, float* __restrict__ y30)
{
    __shared__ __align__(16) char smraw[12416 + 37440 + 1024];   // 50.9 KB
    float* sig = (float*)smraw;                                  // [3104]
    unsigned short* p1T = (unsigned short*)(smraw + 12416);      // phys [260*72]
    float* part = (float*)(smraw + 12416 + 37440);               // phys [8][32]
    float* red  = (float*)(smraw + 12416);                       // enc overlay [2][8][64]
    float* ymat = (float*)p1T;                                   // phys epilogue overlay

    const int bx = blockIdx.x;
    const int type = bx % 3;          // 0,1: encoder; 2: phys
    const int b = bx / 3;
    const int tid = threadIdx.x;
    const int lane = tid & 63, wv = tid >> 6;                    // wv 0..7
    const bf16x8* fr = (const bf16x8*)Frag;

    if (type < 2) {
        // =================== encoder path (R7-verified) ===================
        const float* __restrict__ xb = (type ? S_P : S_V) + (size_t)b * 3072;
        float* hout = type ? hp : hv;
        const int n = lane & 31, kg = lane >> 5;

        #pragma unroll
        for (int i = 0; i < 3; ++i) {
            int idx = tid + i * 512;
            ((float2*)sig)[idx] = ((const float2*)xb)[idx];
        }
        bf16x8 Bf0 = fr[(20 + type * 2) * 64 + lane];   // weights ch 0..31
        bf16x8 Bf1 = fr[(21 + type * 2) * 64 + lane];   // weights ch 32..63
        __syncthreads();

        const f32x16 z = zero16();          // persistent zero-C bank
        float s0[16], s1[16];
        #pragma unroll
        for (int r = 0; r < 16; ++r) { s0[r] = 0.f; s1[r] = 0.f; }

        #pragma unroll 2
        for (int nt = wv; nt < 32; nt += 8) {
            const int t = nt * 32 + n;                 // n = time row of A
            union { unsigned int u[4]; bf16x8 v; } bb;
            bb.u[0] = bb.u[1] = bb.u[2] = bb.u[3] = 0u;
            if (t < 1022) {
                const float* xp = sig + 3 * t;
                if (kg == 0) {          // k=0..7 -> x[3t..3t+7]
                    bb.u[0] = pk2(xp[0], xp[1]); bb.u[1] = pk2(xp[2], xp[3]);
                    bb.u[2] = pk2(xp[4], xp[5]); bb.u[3] = pk2(xp[6], xp[7]);
                } else {                // k=8 -> x[3t+8]; k=15 -> 1.0 (bias col)
                    bb.u[0] = pk2(xp[8], 0.f);
                    bb.u[3] = 0x3F800000u;   // packed (0.0, 1.0) in bf16
                }
            }
            f32x16 y = __builtin_amdgcn_mfma_f32_32x32x16_bf16(bb.v, Bf0, z, 0, 0, 0);
            #pragma unroll
            for (int r = 0; r < 16; ++r) s0[r] += fmaxf(y[r], 0.f);
            y = __builtin_amdgcn_mfma_f32_32x32x16_bf16(bb.v, Bf1, z, 0, 0, 0);
            #pragma unroll
            for (int r = 0; r < 16; ++r) s1[r] += fmaxf(y[r], 0.f);
        }

        // lane-local tree sums (16 -> 1), then cross-wave reduce
        float t0, t1;
        {
            float a0 = (s0[0]+s0[1]) + (s0[2]+s0[3]);
            float a1 = (s0[4]+s0[5]) + (s0[6]+s0[7]);
            float a2 = (s0[8]+s0[9]) + (s0[10]+s0[11]);
            float a3 = (s0[12]+s0[13]) + (s0[14]+s0[15]);
            t0 = (a0 + a1) + (a2 + a3);
            float c0 = (s1[0]+s1[1]) + (s1[2]+s1[3]);
            float c1 = (s1[4]+s1[5]) + (s1[6]+s1[7]);
            float c2 = (s1[8]+s1[9]) + (s1[10]+s1[11]);
            float c3 = (s1[12]+s1[13]) + (s1[14]+s1[15]);
            t1 = (c0 + c1) + (c2 + c3);
        }
        __syncthreads();                 // sig reads done; red overlays p1T region
        red[(0 * 8 + wv) * 64 + lane] = t0;
        red[(1 * 8 + wv) * 64 + lane] = t1;
        __syncthreads();
        if (tid < 64) {                  // tid = channel c
            int half = tid >> 5, c32 = tid & 31;
            float s = 0.f;
            #pragma unroll
            for (int w = 0; w < 8; ++w)
                s += red[(half * 8 + w) * 64 + c32] + red[(half * 8 + w) * 64 + c32 + 32];
            hout[(size_t)b * 64 + tid] = s * (1.0f / 1022.0f);
        }
        return;
    }

    // =================== phys path (R7-verified) ===================
    const float* __restrict__ xb = S_P1 + (size_t)b * 3072;

    #pragma unroll
    for (int i = 0; i < 3; ++i) {
        int idx = tid + i * 512;
        ((float2*)sig)[idx] = ((const float2*)xb)[idx];
    }
    if (tid < 16) ((float2*)sig)[1536 + tid] = make_float2(0.f, 0.f);
    if (tid < 180) ((unsigned int*)(p1T + 255 * P1TS))[tid] = 0u;
    __syncthreads();

    // ---- phase 1 ----
    {
        const int n = lane & 31, kg2 = lane >> 5;
        bf16x8 W10 = fr[24 * 64 + lane];
        bf16x8 W11 = fr[25 * 64 + lane];
        const f32x16 z = zero16();      // persistent zero-C bank
        #pragma unroll 2
        for (int ntl = wv; ntl < 32; ntl += 8) {
            const int t = ntl * 32 + n;
            const float* xp = sig + 3 * t + kg2 * 8;
            union { unsigned int u[4]; bf16x8 v; } bb;
            bb.u[0] = pk2(xp[0], xp[1]);
            bb.u[1] = pk2(xp[2], xp[3]);
            bb.u[2] = pk2(xp[4], xp[5]);
            bb.u[3] = pk2(xp[6], kg2 ? 1.0f : xp[7]);
            f32x16 y = __builtin_amdgcn_mfma_f32_32x32x16_bf16(bb.v, W10, z, 0, 0, 0);
            #pragma unroll
            for (int g4 = 0; g4 < 4; ++g4) {
                const int t4 = ntl * 8 + 2 * g4 + kg2;
                if (t4 < 255) {
                    float p0 = max4(y[4*g4+0], y[4*g4+1], y[4*g4+2], y[4*g4+3]);
                    p1T[t4 * P1TS + n] = (unsigned short)pk2(p0, p0);
                }
            }
            y = __builtin_amdgcn_mfma_f32_32x32x16_bf16(bb.v, W11, z, 0, 0, 0);
            #pragma unroll
            for (int g4 = 0; g4 < 4; ++g4) {
                const int t4 = ntl * 8 + 2 * g4 + kg2;
                if (t4 < 255) {
                    float p1 = max4(y[4*g4+0], y[4*g4+1], y[4*g4+2], y[4*g4+3]);
                    p1T[t4 * P1TS + n + 32] = (unsigned short)pk2(p1, p1);
                }
            }
        }
    }
    __syncthreads();

    // ---- phase 2 ----
    const int m_ = lane & 15, kg16 = lane >> 4;
    f32x4 acc[2][2];
    #pragma unroll
    for (int q = 0; q < 2; ++q) {
        acc[q][0] = (f32x4){0.f, 0.f, 0.f, 0.f};
        acc[q][1] = (f32x4){0.f, 0.f, 0.f, 0.f};
    }
    #pragma unroll 1
    for (int Ks = 0; Ks < 2; ++Ks) {
        bf16x8 Wf[10];
        #pragma unroll
        for (int kk = 0; kk < 5; ++kk) {
            Wf[kk * 2]     = fr[((kk * 2 + Ks) * 2) * 64 + lane];
            Wf[kk * 2 + 1] = fr[((kk * 2 + Ks) * 2 + 1) * 64 + lane];
        }
        #pragma unroll
        for (int kk = 0; kk < 5; ++kk) {
            #pragma unroll
            for (int q = 0; q < 2; ++q) {
                const int row = wv * 32 + q * 16 + m_ + kk;
                const bf16x8 Pf = *(const bf16x8*)(p1T + row * P1TS + Ks * 32 + kg16 * 8);
                acc[q][0] = __builtin_amdgcn_mfma_f32_16x16x32_bf16(Pf, Wf[kk*2],   acc[q][0], 0, 0, 0);
                acc[q][1] = __builtin_amdgcn_mfma_f32_16x16x32_bf16(Pf, Wf[kk*2+1], acc[q][1], 0, 0, 0);
            }
        }
    }
    __syncthreads();

    #pragma unroll
    for (int q = 0; q < 2; ++q) {
        #pragma unroll
        for (int ft = 0; ft < 2; ++ft) {
            f32x4 av = acc[q][ft];
            float p = max4(av[0], av[1], av[2], av[3]);
            int n4 = wv * 8 + q * 4 + kg16;
            ymat[n4 * 36 + ft * 16 + m_] = p;
        }
    }
    __syncthreads();
    if (tid < 256) {
        int w8 = tid >> 5, f = tid & 31;
        if (f < 30) {
            float s = 0.f;
            #pragma unroll 2
            for (int r = w8; r < 62; r += 8) s += ymat[r * 36 + f];
            part[w8 * 32 + f] = s;
        }
    }
    __syncthreads();
    if (tid < 30) {
        float s = 0.f;
        #pragma unroll
        for (int w8 = 0; w8 < 8; ++w8) s += part[w8 * 32 + tid];
        y30[(size_t)b * 30 + tid] = s * (1.0f / 62.0f) + b2[tid];
    }
}

// ---------------------------------------------------------------------------
// Head as batched MFMA GEMMs (unchanged from R6 — verified).
// ---------------------------------------------------------------------------
__global__ __launch_bounds__(256, 2) void head_kernel(
    const int* __restrict__ pairs,
    const float* __restrict__ hv_g, const float* __restrict__ hp_g,
    const float* __restrict__ y30_g,
    const unsigned short* __restrict__ Frag,
    const float* __restrict__ bs_v, const float* __restrict__ bd_v,
    const float* __restrict__ bs_p, const float* __restrict__ bd_p,
    const float* __restrict__ Wf,  const float* __restrict__ bf,
    float* __restrict__ out)
{
    __shared__ __align__(16) float vs_tmp[16][36], ps_tmp[16][36];
    __shared__ __align__(16) float h1l[16][36], h2l[16][36];
    __shared__ __align__(16) float tok[4][16][36];
    __shared__ __align__(16) float qkl[4 * 3144];      // t*3144 + s*196 + c
    __shared__ __align__(16) float qml[16][32];
    __shared__ float wsml[16][4][4];
    __shared__ int pfl[16];
    const int b0 = blockIdx.x * HB;
    const int tid = threadIdx.x, lane = tid & 63, wv = tid >> 6;
    const bf16x8* fr = (const bf16x8*)Frag;
    const int sA = lane & 15, kgA = lane >> 4;
    union U { unsigned int u[4]; bf16x8 v; };

    if (tid < 16) {
        pfl[tid] = pairs[b0 + tid];
        vs_tmp[tid][30] = 0.f; vs_tmp[tid][31] = 1.0f;
        ps_tmp[tid][30] = 0.f; ps_tmp[tid][31] = 1.0f;
        #pragma unroll
        for (int t = 0; t < 4; ++t) { tok[t][tid][30] = 0.f; tok[t][tid][31] = 1.0f; }
    }
    #pragma unroll
    for (int i = 0; i < 2; ++i) {
        int idx = tid + i * 256;
        int s = idx >> 5, o = idx & 31;
        if (o < 30) tok[2][s][o] = y30_g[(size_t)(b0 + s) * 30 + o];
    }

    // ---- stage A ----
    U Av0, Av1, Ap0, Ap1;
    {
        const float* hvp = hv_g + (size_t)(b0 + sA) * 64 + kgA * 8;
        const float* hpp = hp_g + (size_t)(b0 + sA) * 64 + kgA * 8;
        float4 x0 = *(const float4*)(hvp),      x1 = *(const float4*)(hvp + 4);
        float4 x2 = *(const float4*)(hvp + 32), x3 = *(const float4*)(hvp + 36);
        Av0.u[0] = pk2(x0.x, x0.y); Av0.u[1] = pk2(x0.z, x0.w);
        Av0.u[2] = pk2(x1.x, x1.y); Av0.u[3] = pk2(x1.z, x1.w);
        Av1.u[0] = pk2(x2.x, x2.y); Av1.u[1] = pk2(x2.z, x2.w);
        Av1.u[2] = pk2(x3.x, x3.y); Av1.u[3] = pk2(x3.z, x3.w);
        float4 y0 = *(const float4*)(hpp),      y1 = *(const float4*)(hpp + 4);
        float4 y2 = *(const float4*)(hpp + 32), y3 = *(const float4*)(hpp + 36);
        Ap0.u[0] = pk2(y0.x, y0.y); Ap0.u[1] = pk2(y0.z, y0.w);
        Ap0.u[2] = pk2(y1.x, y1.y); Ap0.u[3] = pk2(y1.z, y1.w);
        Ap1.u[0] = pk2(y2.x, y2.y); Ap1.u[1] = pk2(y2.z, y2.w);
        Ap1.u[2] = pk2(y3.x, y3.y); Ap1.u[3] = pk2(y3.z, y3.w);
    }
    {
        f32x4 accv = (f32x4){0.f,0.f,0.f,0.f}, accp = (f32x4){0.f,0.f,0.f,0.f};
        accv = __builtin_amdgcn_mfma_f32_16x16x32_bf16(Av0.v, fr[(26 + wv) * 64 + lane], accv, 0, 0, 0);
        accv = __builtin_amdgcn_mfma_f32_16x16x32_bf16(Av1.v, fr[(30 + wv) * 64 + lane], accv, 0, 0, 0);
        accp = __builtin_amdgcn_mfma_f32_16x16x32_bf16(Ap0.v, fr[(34 + wv) * 64 + lane], accp, 0, 0, 0);
        accp = __builtin_amdgcn_mfma_f32_16x16x32_bf16(Ap1.v, fr[(38 + wv) * 64 + lane], accp, 0, 0, 0);
        int oD = wv * 16 + sA;
        bool lo = oD < 30, hi = (oD >= 30) && (oD < 60);
        float bv = 0.f, bp = 0.f;
        if (lo) { bv = bs_v[oD]; bp = bs_p[oD]; }
        else if (hi) { bv = bd_v[oD - 30]; bp = bd_p[oD - 30]; }
        #pragma unroll
        for (int r = 0; r < 4; ++r) {
            int s = kgA * 4 + r;
            if (lo)      { vs_tmp[s][oD] = accv[r] + bv;  ps_tmp[s][oD] = accp[r] + bp; }
            else if (hi) { tok[3][s][oD-30] = accv[r] + bv; tok[0][s][oD-30] = accp[r] + bp; }
        }
    }
    __syncthreads();

    // ---- stage B ----
    {
        int side = wv >> 1, nt = wv & 1;
        const float (*src)[36] = side ? ps_tmp : vs_tmp;
        const float* ap = &src[sA][kgA * 8];
        float4 x0 = *(const float4*)ap, x1 = *(const float4*)(ap + 4);
        U A;
        A.u[0] = pk2(x0.x, x0.y); A.u[1] = pk2(x0.z, x0.w);
        A.u[2] = pk2(x1.x, x1.y); A.u[3] = pk2(x1.z, x1.w);
        f32x4 acc = (f32x4){0.f,0.f,0.f,0.f};
        acc = __builtin_amdgcn_mfma_f32_16x16x32_bf16(A.v, fr[(42 + nt) * 64 + lane], acc, 0, 0, 0);
        int oD = nt * 16 + sA;
        if (oD < 30) {
            float (*dst)[36] = side ? h2l : h1l;
            #pragma unroll
            for (int r = 0; r < 4; ++r) dst[kgA * 4 + r][oD] = acc[r];
        }
    }
    __syncthreads();

    // ---- LSE soft-OR fusion -> tok[1] ----
    #pragma unroll
    for (int i = 0; i < 2; ++i) {
        int idx = tid + i * 256;
        int s = idx >> 5, o = idx & 31;
        if (o < 30) {
            float h1 = h1l[s][o], h2 = h2l[s][o], h12 = h1 + h2;
            float m1 = fmaxf(h12, fmaxf(h1, h2));
            float lse1 = m1 + logf(2.f*expf(h12 - m1) + expf(h1 - m1) + expf(h2 - m1));
            float m2 = fmaxf(0.f, fmaxf(h1, h2));
            float lse2 = m2 + logf(2.f*expf(-m2) + expf(h1 - m2) + expf(h2 - m2));
            tok[1][s][o] = pfl[s] ? (lse1 - lse2) : h2;
        }
    }
    __syncthreads();

    // ---- stage C ----
    {
        const float* ap = &tok[wv][sA][kgA * 8];
        float4 x0 = *(const float4*)ap, x1 = *(const float4*)(ap + 4);
        U A;
        A.u[0] = pk2(x0.x, x0.y); A.u[1] = pk2(x0.z, x0.w);
        A.u[2] = pk2(x1.x, x1.y); A.u[3] = pk2(x1.z, x1.w);
        #pragma unroll
        for (int nt = 0; nt < 12; ++nt) {
            f32x4 acc = (f32x4){0.f,0.f,0.f,0.f};
            acc = __builtin_amdgcn_mfma_f32_16x16x32_bf16(A.v, fr[(44 + nt) * 64 + lane], acc, 0, 0, 0);
            int c = nt * 16 + sA;
            #pragma unroll
            for (int r = 0; r < 4; ++r)
                qkl[wv * 3144 + (kgA * 4 + r) * 196 + c] = acc[r];
        }
    }
    __syncthreads();

    // ---- stage D ----
    #pragma unroll
    for (int i = 0; i < 2; ++i) {
        int idx = tid + i * 256;
        int s = idx >> 5, d = idx & 31;
        float q0 = qkl[0*3144 + s*196 + d], q1 = qkl[1*3144 + s*196 + d];
        float q2 = qkl[2*3144 + s*196 + d], q3 = qkl[3*3144 + s*196 + d];
        qml[s][d] = pfl[s] ? (q0 + q1 + q2 + q3) * 0.25f
                           : (q0 + q1 + q2) * (1.f / 3.f);
    }
    __syncthreads();
    {
        int s = tid >> 4, n = (tid >> 2) & 3, t = tid & 3;
        const float4* kp = (const float4*)&qkl[t*3144 + s*196 + 64 + 32*n];
        const float4* qp = (const float4*)&qml[s][0];
        float a = 0.f;
        #pragma unroll
        for (int d4 = 0; d4 < 8; ++d4) {
            float4 k4 = kp[d4], q4 = qp[d4];
            a += k4.x*q4.x + k4.y*q4.y + k4.z*q4.z + k4.w*q4.w;
        }
        a *= 0.17677669529663687f;
        if (t == 3 && pfl[s] == 0) a = -INFINITY;
        float m = maxq(a);
        float e = expf(a - m);
        float ssum = sumq(e);
        wsml[s][n][t] = e / ssum;
    }
    __syncthreads();
    if (tid < 64) {
        int s = tid >> 2, n = tid & 3;
        float w0 = wsml[s][n][0], w1 = wsml[s][n][1];
        float w2 = wsml[s][n][2], w3 = wsml[s][n][3];
        const float4* v0 = (const float4*)&qkl[0*3144 + s*196 + 32];
        const float4* v1 = (const float4*)&qkl[1*3144 + s*196 + 32];
        const float4* v2 = (const float4*)&qkl[2*3144 + s*196 + 32];
        const float4* v3 = (const float4*)&qkl[3*3144 + s*196 + 32];
        float acc = bf[n];
        #pragma unroll
        for (int d4 = 0; d4 < 8; ++d4) {
            float4 a0 = v0[d4], a1 = v1[d4], a2 = v2[d4], a3 = v3[d4];
            int d = d4 * 4;
            float f0 = w0*a0.x + w1*a1.x + w2*a2.x + w3*a3.x;
            float f1 = w0*a0.y + w1*a1.y + w2*a2.y + w3*a3.y;
            float f2 = w0*a0.z + w1*a1.z + w2*a2.z + w3*a3.z;
            float f3 = w0*a0.w + w1*a1.w + w2*a2.w + w3*a3.w;
            acc += f0 * Wf[d*4 + n]     + f1 * Wf[(d+1)*4 + n]
                 + f2 * Wf[(d+2)*4 + n] + f3 * Wf[(d+3)*4 + n];
        }
        out[(size_t)(b0 + s) * 4 + n] = acc;
    }
}

// ---------------------------------------------------------------------------
extern "C" void kernel_launch(void* const* d_in, const int* in_sizes, int n_in,
                              void* d_out, int out_size, void* d_ws, size_t ws_size,
                              hipStream_t stream)
{
    const int*   pairs = (const int*)  d_in[0];
    const float* S_V   = (const float*)d_in[1];
    const float* S_P   = (const float*)d_in[2];
    const float* S_P1  = (const float*)d_in[3];
    const float* Wc_v  = (const float*)d_in[4];
    const float* bc_v  = (const float*)d_in[5];
    const float* Ws_v  = (const float*)d_in[6];
    const float* bs_v  = (const float*)d_in[7];
    const float* Wd_v  = (const float*)d_in[8];
    const float* bd_v  = (const float*)d_in[9];
    const float* Wc_p  = (const float*)d_in[10];
    const float* bc_p  = (const float*)d_in[11];
    const float* Ws_p  = (const float*)d_in[12];
    const float* bs_p  = (const float*)d_in[13];
    const float* Wd_p  = (const float*)d_in[14];
    const float* bd_p  = (const float*)d_in[15];
    const float* Wsp   = (const float*)d_in[16];
    const float* bsp   = (const float*)d_in[17];
    const float* W1    = (const float*)d_in[18];
    const float* b1    = (const float*)d_in[19];
    const float* W2    = (const float*)d_in[20];
    const float* b2    = (const float*)d_in[21];
    const float* Wa    = (const float*)d_in[22];
    const float* ba    = (const float*)d_in[23];
    const float* Wf    = (const float*)d_in[24];
    const float* bf    = (const float*)d_in[25];
    float* out = (float*)d_out;

    // ws: h_v[B][64] | h_p[B][64] | y30[B][30] | frags (56 x 64 x 16B)
    float* ws  = (float*)d_ws;
    float* h_v = ws;
    float* h_p = ws + (size_t)B_ * 64;
    float* y30 = ws + (size_t)2 * B_ * 64;
    unsigned short* Frag = (unsigned short*)(ws + (size_t)2 * B_ * 64 + (size_t)B_ * 30);

    prep_frags<<<14, 256, 0, stream>>>(W2, Wc_v, Wc_p, W1, bc_v, bc_p, b1,
                                       Ws_v, Wd_v, Ws_p, Wd_p, Wsp, bsp, Wa, ba,
                                       Frag);
    enc_phys_kernel<<<3 * B_, 512, 0, stream>>>(
        S_V, S_P, S_P1, Frag, b2, h_v, h_p, y30);
    head_kernel<<<B_ / HB, 256, 0, stream>>>(
        pairs, h_v, h_p, y30, Frag,
        bs_v, bd_v, bs_p, bd_p, Wf, bf, out);
}

// Round 10
// 269.945 us; speedup vs baseline: 1.0148x; 1.0148x over previous
//
#include <hip/hip_runtime.h>
#include <math.h>

#define B_   4096
#define HB   16      // samples per head block

typedef __attribute__((ext_vector_type(8)))  short bf16x8;   // 8 bf16 = 4 VGPR
typedef __attribute__((ext_vector_type(4)))  float f32x4;
typedef __attribute__((ext_vector_type(16))) float f32x16;

// packed f32->bf16 RNE, single VALU instruction (gfx950; no builtin — T12 recipe)
__device__ __forceinline__ unsigned int pk2(float a, float b) {
    unsigned int r;
    asm("v_cvt_pk_bf16_f32 %0, %1, %2" : "=v"(r) : "v"(a), "v"(b));
    return r;
}
__device__ __forceinline__ f32x16 zero16() {
    f32x16 z;
    #pragma unroll
    for (int i = 0; i < 16; ++i) z[i] = 0.f;
    return z;
}
__device__ __forceinline__ float max4(float a, float b, float c, float d) {
    return fmaxf(fmaxf(a, b), fmaxf(c, d));
}
// quad (lanes t=0..3) all-reduce max / sum via DPP
__device__ __forceinline__ float maxq(float v) {
    int y1 = __builtin_amdgcn_update_dpp(0, __float_as_int(v), 0xB1, 0xF, 0xF, true);
    float v1 = fmaxf(v, __int_as_float(y1));
    int y2 = __builtin_amdgcn_update_dpp(0, __float_as_int(v1), 0x4E, 0xF, 0xF, true);
    return fmaxf(v1, __int_as_float(y2));
}
__device__ __forceinline__ float sumq(float v) {
    int y1 = __builtin_amdgcn_update_dpp(0, __float_as_int(v), 0xB1, 0xF, 0xF, true);
    float v1 = v + __int_as_float(y1);
    int y2 = __builtin_amdgcn_update_dpp(0, __float_as_int(v1), 0x4E, 0xF, 0xF, true);
    return v1 + __int_as_float(y2);
}

// ---------------------------------------------------------------------------
// prep: all MFMA fragments (56 x 64 lanes x 16B). A and B fragment lane
// layouts are identical on gfx950 (16x16x32: n=lane&15, k=(lane>>4)*8+j).
//  e 0..19 : phys phase-2 (16x16x32), e=(kk*2+Ks)*2+ftile
//  e 20..23: encoder conv (32x32x16), e-20=enc*2+mt; j<9 W, j==15 bias
//            (j=9..14 are EXACT zeros — the encoder B-build relies on this
//             to feed don't-care x values at those k positions)
//  e 24..25: phys phase-1 (32x32x16), mt=e-24;       j<15 W, j==15 bias
//  e 26..41: head stage-A [Ws|Wd] concat, K=64 N=64(o<60 valid):
//            e = 26 + side*8 + Kc*4 + ntile   (side 0=v, 1=p)
//  e 42..43: head Wsp, K=32 (k<30 W, k31 bsp), N=32 (o<30): e = 42+ntile
//  e 44..55: head Wa,  K=32 (k<30 W, k31 ba),  N=192:       e = 44+ntile
// ---------------------------------------------------------------------------
__global__ void prep_frags(const float* __restrict__ W2,
                           const float* __restrict__ Wc_v,
                           const float* __restrict__ Wc_p,
                           const float* __restrict__ W1,
                           const float* __restrict__ bc_v,
                           const float* __restrict__ bc_p,
                           const float* __restrict__ b1,
                           const float* __restrict__ Ws_v,
                           const float* __restrict__ Wd_v,
                           const float* __restrict__ Ws_p,
                           const float* __restrict__ Wd_p,
                           const float* __restrict__ Wsp,
                           const float* __restrict__ bsp,
                           const float* __restrict__ Wa,
                           const float* __restrict__ ba,
                           unsigned short* __restrict__ ws_frag)
{
    int gid = blockIdx.x * 256 + threadIdx.x;
    if (gid >= 56 * 64) return;
    int lane = gid & 63, e = gid >> 6;
    unsigned int w[4];
    if (e < 20) {
        int ft = e & 1, Ks = (e >> 1) & 1, kk = e >> 2;
        int m = lane & 15, kg = lane >> 4;
        int f = ft * 16 + m;
        #pragma unroll
        for (int p = 0; p < 4; ++p) {
            int i0 = Ks * 32 + kg * 8 + 2 * p;
            float v0 = (f < 30) ? W2[f * 320 + i0 * 5 + kk] : 0.f;
            float v1 = (f < 30) ? W2[f * 320 + (i0 + 1) * 5 + kk] : 0.f;
            w[p] = pk2(v0, v1);
        }
    } else if (e < 24) {
        int e2 = e - 20, enc = e2 >> 1, mt = e2 & 1;
        const float* Wc = enc ? Wc_p : Wc_v;
        const float* bc = enc ? bc_p : bc_v;
        int c = mt * 32 + (lane & 31), kg = lane >> 5;
        #pragma unroll
        for (int p = 0; p < 4; ++p) {
            int j0 = kg * 8 + 2 * p, j1 = j0 + 1;
            float v0 = (j0 < 9) ? Wc[c * 9 + (j0 % 3) * 3 + (j0 / 3)] : 0.f;
            float v1 = (j1 < 9) ? Wc[c * 9 + (j1 % 3) * 3 + (j1 / 3)]
                                : (j1 == 15 ? bc[c] : 0.f);
            w[p] = pk2(v0, v1);
        }
    } else if (e < 26) {
        int mt = e - 24;
        int c = mt * 32 + (lane & 31), kg = lane >> 5;
        #pragma unroll
        for (int p = 0; p < 4; ++p) {
            int j0 = kg * 8 + 2 * p, j1 = j0 + 1;
            float v0 = (j0 < 15) ? W1[c * 15 + (j0 % 3) * 5 + (j0 / 3)] : 0.f;
            float v1 = (j1 < 15) ? W1[c * 15 + (j1 % 3) * 5 + (j1 / 3)]
                                 : (j1 == 15 ? b1[c] : 0.f);
            w[p] = pk2(v0, v1);
        }
    } else if (e < 42) {
        int e2 = e - 26;
        int side = e2 >> 3, idx = e2 & 7;
        int Kc = idx >> 2, nt = idx & 3;
        const float* Ws = side ? Ws_p : Ws_v;
        const float* Wd = side ? Wd_p : Wd_v;
        int o = nt * 16 + (lane & 15), kg = lane >> 4;
        #pragma unroll
        for (int p = 0; p < 4; ++p) {
            int j0 = Kc * 32 + kg * 8 + 2 * p, j1 = j0 + 1;
            float v0 = (o < 30) ? Ws[j0 * 30 + o] : (o < 60 ? Wd[j0 * 30 + o - 30] : 0.f);
            float v1 = (o < 30) ? Ws[j1 * 30 + o] : (o < 60 ? Wd[j1 * 30 + o - 30] : 0.f);
            w[p] = pk2(v0, v1);
        }
    } else if (e < 44) {
        int nt = e - 42;
        int o = nt * 16 + (lane & 15), kg = lane >> 4;
        #pragma unroll
        for (int p = 0; p < 4; ++p) {
            int j0 = kg * 8 + 2 * p, j1 = j0 + 1;
            float v0 = 0.f, v1 = 0.f;
            if (o < 30) {
                v0 = (j0 < 30) ? Wsp[j0 * 30 + o] : (j0 == 31 ? bsp[o] : 0.f);
                v1 = (j1 < 30) ? Wsp[j1 * 30 + o] : (j1 == 31 ? bsp[o] : 0.f);
            }
            w[p] = pk2(v0, v1);
        }
    } else {
        int nt = e - 44;
        int c = nt * 16 + (lane & 15), kg = lane >> 4;
        #pragma unroll
        for (int p = 0; p < 4; ++p) {
            int j0 = kg * 8 + 2 * p, j1 = j0 + 1;
            float v0 = (j0 < 30) ? Wa[j0 * 192 + c] : (j0 == 31 ? ba[c] : 0.f);
            float v1 = (j1 < 30) ? Wa[j1 * 192 + c] : (j1 == 31 ? ba[c] : 0.f);
            w[p] = pk2(v0, v1);
        }
    }
    ((uint4*)ws_frag)[gid] = make_uint4(w[0], w[1], w[2], w[3]);
}

// ---------------------------------------------------------------------------
// MERGED encode + phys. grid = 3*B_, type = bx%3 (0: enc S_V, 1: enc S_P,
// 2: phys S_P1). R10: encoder inner loop made STRAIGHT-LINE like phys p1:
//  - unified per-lane loads xp = sig + 3t + kg*8 (garbage x at k=9..14 is
//    annihilated by the A-fragment's exact zeros there);
//  - t<1022 guard moved from a divergent load-branch to a keep-factor in
//    the accumulate: s[r] = fmaf(keep, relu(y[r]), s[r]) — same op count
//    as +=, pad rows multiplied by 0 before touching the sum;
//  - sig zero-padded to 3104 (reads reach 3084), same as phys.
// Math identical to R9 (verified).
// ---------------------------------------------------------------------------
#define P1TS 72
__global__ __launch_bounds__(512, 4) void enc_phys_kernel(
    const float* __restrict__ S_V, const float* __restrict__ S_P,
    const float* __restrict__ S_P1,
    const unsigned short* __restrict__ Frag,
    const float* __restrict__ b2,
    float* __restrict__ hv, float* __restrict__ hp, float* __restrict__ y30)
{
    __shared__ __align__(16) char smraw[12416 + 37440 + 1024];   // 50.9 KB
    float* sig = (float*)smraw;                                  // [3104]
    unsigned short* p1T = (unsigned short*)(smraw + 12416);      // phys [260*72]
    float* part = (float*)(smraw + 12416 + 37440);               // phys [8][32]
    float* red  = (float*)(smraw + 12416);                       // enc overlay [2][8][64]
    float* ymat = (float*)p1T;                                   // phys epilogue overlay

    const int bx = blockIdx.x;
    const int type = bx % 3;          // 0,1: encoder; 2: phys
    const int b = bx / 3;
    const int tid = threadIdx.x;
    const int lane = tid & 63, wv = tid >> 6;                    // wv 0..7
    const bf16x8* fr = (const bf16x8*)Frag;

    if (type < 2) {
        // =================== encoder path ===================
        const float* __restrict__ xb = (type ? S_P : S_V) + (size_t)b * 3072;
        float* hout = type ? hp : hv;
        const int n = lane & 31, kg = lane >> 5;

        #pragma unroll
        for (int i = 0; i < 3; ++i) {
            int idx = tid + i * 512;
            ((float2*)sig)[idx] = ((const float2*)xb)[idx];
        }
        if (tid < 16) ((float2*)sig)[1536 + tid] = make_float2(0.f, 0.f);
        bf16x8 Bf0 = fr[(20 + type * 2) * 64 + lane];   // weights ch 0..31
        bf16x8 Bf1 = fr[(21 + type * 2) * 64 + lane];   // weights ch 32..63
        __syncthreads();

        const f32x16 z = zero16();          // persistent zero-C bank
        float s0[16], s1[16];
        #pragma unroll
        for (int r = 0; r < 16; ++r) { s0[r] = 0.f; s1[r] = 0.f; }

        #pragma unroll 2
        for (int nt = wv; nt < 32; nt += 8) {
            const int t = nt * 32 + n;                 // n = time row of A
            const float keep = (t < 1022) ? 1.0f : 0.0f;
            const float* xp = sig + 3 * t + kg * 8;
            union { unsigned int u[4]; bf16x8 v; } bb;
            // kg=0: k=0..7 real taps. kg=1: k=8 real tap; k=9..14 feed
            // arbitrary x — annihilated by A's exact zeros; k=15 bias col.
            bb.u[0] = pk2(xp[0], xp[1]);
            bb.u[1] = pk2(xp[2], xp[3]);
            bb.u[2] = pk2(xp[4], xp[5]);
            bb.u[3] = pk2(xp[6], kg ? 1.0f : xp[7]);
            f32x16 y = __builtin_amdgcn_mfma_f32_32x32x16_bf16(bb.v, Bf0, z, 0, 0, 0);
            #pragma unroll
            for (int r = 0; r < 16; ++r) s0[r] = fmaf(keep, fmaxf(y[r], 0.f), s0[r]);
            y = __builtin_amdgcn_mfma_f32_32x32x16_bf16(bb.v, Bf1, z, 0, 0, 0);
            #pragma unroll
            for (int r = 0; r < 16; ++r) s1[r] = fmaf(keep, fmaxf(y[r], 0.f), s1[r]);
        }

        // lane-local tree sums (16 -> 1), then cross-wave reduce
        float t0, t1;
        {
            float a0 = (s0[0]+s0[1]) + (s0[2]+s0[3]);
            float a1 = (s0[4]+s0[5]) + (s0[6]+s0[7]);
            float a2 = (s0[8]+s0[9]) + (s0[10]+s0[11]);
            float a3 = (s0[12]+s0[13]) + (s0[14]+s0[15]);
            t0 = (a0 + a1) + (a2 + a3);
            float c0 = (s1[0]+s1[1]) + (s1[2]+s1[3]);
            float c1 = (s1[4]+s1[5]) + (s1[6]+s1[7]);
            float c2 = (s1[8]+s1[9]) + (s1[10]+s1[11]);
            float c3 = (s1[12]+s1[13]) + (s1[14]+s1[15]);
            t1 = (c0 + c1) + (c2 + c3);
        }
        __syncthreads();                 // sig reads done; red overlays p1T region
        red[(0 * 8 + wv) * 64 + lane] = t0;
        red[(1 * 8 + wv) * 64 + lane] = t1;
        __syncthreads();
        if (tid < 64) {                  // tid = channel c
            int half = tid >> 5, c32 = tid & 31;
            float s = 0.f;
            #pragma unroll
            for (int w = 0; w < 8; ++w)
                s += red[(half * 8 + w) * 64 + c32] + red[(half * 8 + w) * 64 + c32 + 32];
            hout[(size_t)b * 64 + tid] = s * (1.0f / 1022.0f);
        }
        return;
    }

    // =================== phys path (R7-verified) ===================
    const float* __restrict__ xb = S_P1 + (size_t)b * 3072;

    #pragma unroll
    for (int i = 0; i < 3; ++i) {
        int idx = tid + i * 512;
        ((float2*)sig)[idx] = ((const float2*)xb)[idx];
    }
    if (tid < 16) ((float2*)sig)[1536 + tid] = make_float2(0.f, 0.f);
    if (tid < 180) ((unsigned int*)(p1T + 255 * P1TS))[tid] = 0u;
    __syncthreads();

    // ---- phase 1 ----
    {
        const int n = lane & 31, kg2 = lane >> 5;
        bf16x8 W10 = fr[24 * 64 + lane];
        bf16x8 W11 = fr[25 * 64 + lane];
        const f32x16 z = zero16();      // persistent zero-C bank
        #pragma unroll 2
        for (int ntl = wv; ntl < 32; ntl += 8) {
            const int t = ntl * 32 + n;
            const float* xp = sig + 3 * t + kg2 * 8;
            union { unsigned int u[4]; bf16x8 v; } bb;
            bb.u[0] = pk2(xp[0], xp[1]);
            bb.u[1] = pk2(xp[2], xp[3]);
            bb.u[2] = pk2(xp[4], xp[5]);
            bb.u[3] = pk2(xp[6], kg2 ? 1.0f : xp[7]);
            f32x16 y = __builtin_amdgcn_mfma_f32_32x32x16_bf16(bb.v, W10, z, 0, 0, 0);
            #pragma unroll
            for (int g4 = 0; g4 < 4; ++g4) {
                const int t4 = ntl * 8 + 2 * g4 + kg2;
                if (t4 < 255) {
                    float p0 = max4(y[4*g4+0], y[4*g4+1], y[4*g4+2], y[4*g4+3]);
                    p1T[t4 * P1TS + n] = (unsigned short)pk2(p0, p0);
                }
            }
            y = __builtin_amdgcn_mfma_f32_32x32x16_bf16(bb.v, W11, z, 0, 0, 0);
            #pragma unroll
            for (int g4 = 0; g4 < 4; ++g4) {
                const int t4 = ntl * 8 + 2 * g4 + kg2;
                if (t4 < 255) {
                    float p1 = max4(y[4*g4+0], y[4*g4+1], y[4*g4+2], y[4*g4+3]);
                    p1T[t4 * P1TS + n + 32] = (unsigned short)pk2(p1, p1);
                }
            }
        }
    }
    __syncthreads();

    // ---- phase 2 ----
    const int m_ = lane & 15, kg16 = lane >> 4;
    f32x4 acc[2][2];
    #pragma unroll
    for (int q = 0; q < 2; ++q) {
        acc[q][0] = (f32x4){0.f, 0.f, 0.f, 0.f};
        acc[q][1] = (f32x4){0.f, 0.f, 0.f, 0.f};
    }
    #pragma unroll 1
    for (int Ks = 0; Ks < 2; ++Ks) {
        bf16x8 Wf[10];
        #pragma unroll
        for (int kk = 0; kk < 5; ++kk) {
            Wf[kk * 2]     = fr[((kk * 2 + Ks) * 2) * 64 + lane];
            Wf[kk * 2 + 1] = fr[((kk * 2 + Ks) * 2 + 1) * 64 + lane];
        }
        #pragma unroll
        for (int kk = 0; kk < 5; ++kk) {
            #pragma unroll
            for (int q = 0; q < 2; ++q) {
                const int row = wv * 32 + q * 16 + m_ + kk;
                const bf16x8 Pf = *(const bf16x8*)(p1T + row * P1TS + Ks * 32 + kg16 * 8);
                acc[q][0] = __builtin_amdgcn_mfma_f32_16x16x32_bf16(Pf, Wf[kk*2],   acc[q][0], 0, 0, 0);
                acc[q][1] = __builtin_amdgcn_mfma_f32_16x16x32_bf16(Pf, Wf[kk*2+1], acc[q][1], 0, 0, 0);
            }
        }
    }
    __syncthreads();

    #pragma unroll
    for (int q = 0; q < 2; ++q) {
        #pragma unroll
        for (int ft = 0; ft < 2; ++ft) {
            f32x4 av = acc[q][ft];
            float p = max4(av[0], av[1], av[2], av[3]);
            int n4 = wv * 8 + q * 4 + kg16;
            ymat[n4 * 36 + ft * 16 + m_] = p;
        }
    }
    __syncthreads();
    if (tid < 256) {
        int w8 = tid >> 5, f = tid & 31;
        if (f < 30) {
            float s = 0.f;
            #pragma unroll 2
            for (int r = w8; r < 62; r += 8) s += ymat[r * 36 + f];
            part[w8 * 32 + f] = s;
        }
    }
    __syncthreads();
    if (tid < 30) {
        float s = 0.f;
        #pragma unroll
        for (int w8 = 0; w8 < 8; ++w8) s += part[w8 * 32 + tid];
        y30[(size_t)b * 30 + tid] = s * (1.0f / 62.0f) + b2[tid];
    }
}

// ---------------------------------------------------------------------------
// Head as batched MFMA GEMMs (unchanged from R6 — verified).
// ---------------------------------------------------------------------------
__global__ __launch_bounds__(256, 2) void head_kernel(
    const int* __restrict__ pairs,
    const float* __restrict__ hv_g, const float* __restrict__ hp_g,
    const float* __restrict__ y30_g,
    const unsigned short* __restrict__ Frag,
    const float* __restrict__ bs_v, const float* __restrict__ bd_v,
    const float* __restrict__ bs_p, const float* __restrict__ bd_p,
    const float* __restrict__ Wf,  const float* __restrict__ bf,
    float* __restrict__ out)
{
    __shared__ __align__(16) float vs_tmp[16][36], ps_tmp[16][36];
    __shared__ __align__(16) float h1l[16][36], h2l[16][36];
    __shared__ __align__(16) float tok[4][16][36];
    __shared__ __align__(16) float qkl[4 * 3144];      // t*3144 + s*196 + c
    __shared__ __align__(16) float qml[16][32];
    __shared__ float wsml[16][4][4];
    __shared__ int pfl[16];
    const int b0 = blockIdx.x * HB;
    const int tid = threadIdx.x, lane = tid & 63, wv = tid >> 6;
    const bf16x8* fr = (const bf16x8*)Frag;
    const int sA = lane & 15, kgA = lane >> 4;
    union U { unsigned int u[4]; bf16x8 v; };

    if (tid < 16) {
        pfl[tid] = pairs[b0 + tid];
        vs_tmp[tid][30] = 0.f; vs_tmp[tid][31] = 1.0f;
        ps_tmp[tid][30] = 0.f; ps_tmp[tid][31] = 1.0f;
        #pragma unroll
        for (int t = 0; t < 4; ++t) { tok[t][tid][30] = 0.f; tok[t][tid][31] = 1.0f; }
    }
    #pragma unroll
    for (int i = 0; i < 2; ++i) {
        int idx = tid + i * 256;
        int s = idx >> 5, o = idx & 31;
        if (o < 30) tok[2][s][o] = y30_g[(size_t)(b0 + s) * 30 + o];
    }

    // ---- stage A ----
    U Av0, Av1, Ap0, Ap1;
    {
        const float* hvp = hv_g + (size_t)(b0 + sA) * 64 + kgA * 8;
        const float* hpp = hp_g + (size_t)(b0 + sA) * 64 + kgA * 8;
        float4 x0 = *(const float4*)(hvp),      x1 = *(const float4*)(hvp + 4);
        float4 x2 = *(const float4*)(hvp + 32), x3 = *(const float4*)(hvp + 36);
        Av0.u[0] = pk2(x0.x, x0.y); Av0.u[1] = pk2(x0.z, x0.w);
        Av0.u[2] = pk2(x1.x, x1.y); Av0.u[3] = pk2(x1.z, x1.w);
        Av1.u[0] = pk2(x2.x, x2.y); Av1.u[1] = pk2(x2.z, x2.w);
        Av1.u[2] = pk2(x3.x, x3.y); Av1.u[3] = pk2(x3.z, x3.w);
        float4 y0 = *(const float4*)(hpp),      y1 = *(const float4*)(hpp + 4);
        float4 y2 = *(const float4*)(hpp + 32), y3 = *(const float4*)(hpp + 36);
        Ap0.u[0] = pk2(y0.x, y0.y); Ap0.u[1] = pk2(y0.z, y0.w);
        Ap0.u[2] = pk2(y1.x, y1.y); Ap0.u[3] = pk2(y1.z, y1.w);
        Ap1.u[0] = pk2(y2.x, y2.y); Ap1.u[1] = pk2(y2.z, y2.w);
        Ap1.u[2] = pk2(y3.x, y3.y); Ap1.u[3] = pk2(y3.z, y3.w);
    }
    {
        f32x4 accv = (f32x4){0.f,0.f,0.f,0.f}, accp = (f32x4){0.f,0.f,0.f,0.f};
        accv = __builtin_amdgcn_mfma_f32_16x16x32_bf16(Av0.v, fr[(26 + wv) * 64 + lane], accv, 0, 0, 0);
        accv = __builtin_amdgcn_mfma_f32_16x16x32_bf16(Av1.v, fr[(30 + wv) * 64 + lane], accv, 0, 0, 0);
        accp = __builtin_amdgcn_mfma_f32_16x16x32_bf16(Ap0.v, fr[(34 + wv) * 64 + lane], accp, 0, 0, 0);
        accp = __builtin_amdgcn_mfma_f32_16x16x32_bf16(Ap1.v, fr[(38 + wv) * 64 + lane], accp, 0, 0, 0);
        int oD = wv * 16 + sA;
        bool lo = oD < 30, hi = (oD >= 30) && (oD < 60);
        float bv = 0.f, bp = 0.f;
        if (lo) { bv = bs_v[oD]; bp = bs_p[oD]; }
        else if (hi) { bv = bd_v[oD - 30]; bp = bd_p[oD - 30]; }
        #pragma unroll
        for (int r = 0; r < 4; ++r) {
            int s = kgA * 4 + r;
            if (lo)      { vs_tmp[s][oD] = accv[r] + bv;  ps_tmp[s][oD] = accp[r] + bp; }
            else if (hi) { tok[3][s][oD-30] = accv[r] + bv; tok[0][s][oD-30] = accp[r] + bp; }
        }
    }
    __syncthreads();

    // ---- stage B ----
    {
        int side = wv >> 1, nt = wv & 1;
        const float (*src)[36] = side ? ps_tmp : vs_tmp;
        const float* ap = &src[sA][kgA * 8];
        float4 x0 = *(const float4*)ap, x1 = *(const float4*)(ap + 4);
        U A;
        A.u[0] = pk2(x0.x, x0.y); A.u[1] = pk2(x0.z, x0.w);
        A.u[2] = pk2(x1.x, x1.y); A.u[3] = pk2(x1.z, x1.w);
        f32x4 acc = (f32x4){0.f,0.f,0.f,0.f};
        acc = __builtin_amdgcn_mfma_f32_16x16x32_bf16(A.v, fr[(42 + nt) * 64 + lane], acc, 0, 0, 0);
        int oD = nt * 16 + sA;
        if (oD < 30) {
            float (*dst)[36] = side ? h2l : h1l;
            #pragma unroll
            for (int r = 0; r < 4; ++r) dst[kgA * 4 + r][oD] = acc[r];
        }
    }
    __syncthreads();

    // ---- LSE soft-OR fusion -> tok[1] ----
    #pragma unroll
    for (int i = 0; i < 2; ++i) {
        int idx = tid + i * 256;
        int s = idx >> 5, o = idx & 31;
        if (o < 30) {
            float h1 = h1l[s][o], h2 = h2l[s][o], h12 = h1 + h2;
            float m1 = fmaxf(h12, fmaxf(h1, h2));
            float lse1 = m1 + logf(2.f*expf(h12 - m1) + expf(h1 - m1) + expf(h2 - m1));
            float m2 = fmaxf(0.f, fmaxf(h1, h2));
            float lse2 = m2 + logf(2.f*expf(-m2) + expf(h1 - m2) + expf(h2 - m2));
            tok[1][s][o] = pfl[s] ? (lse1 - lse2) : h2;
        }
    }
    __syncthreads();

    // ---- stage C ----
    {
        const float* ap = &tok[wv][sA][kgA * 8];
        float4 x0 = *(const float4*)ap, x1 = *(const float4*)(ap + 4);
        U A;
        A.u[0] = pk2(x0.x, x0.y); A.u[1] = pk2(x0.z, x0.w);
        A.u[2] = pk2(x1.x, x1.y); A.u[3] = pk2(x1.z, x1.w);
        #pragma unroll
        for (int nt = 0; nt < 12; ++nt) {
            f32x4 acc = (f32x4){0.f,0.f,0.f,0.f};
            acc = __builtin_amdgcn_mfma_f32_16x16x32_bf16(A.v, fr[(44 + nt) * 64 + lane], acc, 0, 0, 0);
            int c = nt * 16 + sA;
            #pragma unroll
            for (int r = 0; r < 4; ++r)
                qkl[wv * 3144 + (kgA * 4 + r) * 196 + c] = acc[r];
        }
    }
    __syncthreads();

    // ---- stage D ----
    #pragma unroll
    for (int i = 0; i < 2; ++i) {
        int idx = tid + i * 256;
        int s = idx >> 5, d = idx & 31;
        float q0 = qkl[0*3144 + s*196 + d], q1 = qkl[1*3144 + s*196 + d];
        float q2 = qkl[2*3144 + s*196 + d], q3 = qkl[3*3144 + s*196 + d];
        qml[s][d] = pfl[s] ? (q0 + q1 + q2 + q3) * 0.25f
                           : (q0 + q1 + q2) * (1.f / 3.f);
    }
    __syncthreads();
    {
        int s = tid >> 4, n = (tid >> 2) & 3, t = tid & 3;
        const float4* kp = (const float4*)&qkl[t*3144 + s*196 + 64 + 32*n];
        const float4* qp = (const float4*)&qml[s][0];
        float a = 0.f;
        #pragma unroll
        for (int d4 = 0; d4 < 8; ++d4) {
            float4 k4 = kp[d4], q4 = qp[d4];
            a += k4.x*q4.x + k4.y*q4.y + k4.z*q4.z + k4.w*q4.w;
        }
        a *= 0.17677669529663687f;
        if (t == 3 && pfl[s] == 0) a = -INFINITY;
        float m = maxq(a);
        float e = expf(a - m);
        float ssum = sumq(e);
        wsml[s][n][t] = e / ssum;
    }
    __syncthreads();
    if (tid < 64) {
        int s = tid >> 2, n = tid & 3;
        float w0 = wsml[s][n][0], w1 = wsml[s][n][1];
        float w2 = wsml[s][n][2], w3 = wsml[s][n][3];
        const float4* v0 = (const float4*)&qkl[0*3144 + s*196 + 32];
        const float4* v1 = (const float4*)&qkl[1*3144 + s*196 + 32];
        const float4* v2 = (const float4*)&qkl[2*3144 + s*196 + 32];
        const float4* v3 = (const float4*)&qkl[3*3144 + s*196 + 32];
        float acc = bf[n];
        #pragma unroll
        for (int d4 = 0; d4 < 8; ++d4) {
            float4 a0 = v0[d4], a1 = v1[d4], a2 = v2[d4], a3 = v3[d4];
            int d = d4 * 4;
            float f0 = w0*a0.x + w1*a1.x + w2*a2.x + w3*a3.x;
            float f1 = w0*a0.y + w1*a1.y + w2*a2.y + w3*a3.y;
            float f2 = w0*a0.z + w1*a1.z + w2*a2.z + w3*a3.z;
            float f3 = w0*a0.w + w1*a1.w + w2*a2.w + w3*a3.w;
            acc += f0 * Wf[d*4 + n]     + f1 * Wf[(d+1)*4 + n]
                 + f2 * Wf[(d+2)*4 + n] + f3 * Wf[(d+3)*4 + n];
        }
        out[(size_t)(b0 + s) * 4 + n] = acc;
    }
}

// ---------------------------------------------------------------------------
extern "C" void kernel_launch(void* const* d_in, const int* in_sizes, int n_in,
                              void* d_out, int out_size, void* d_ws, size_t ws_size,
                              hipStream_t stream)
{
    const int*   pairs = (const int*)  d_in[0];
    const float* S_V   = (const float*)d_in[1];
    const float* S_P   = (const float*)d_in[2];
    const float* S_P1  = (const float*)d_in[3];
    const float* Wc_v  = (const float*)d_in[4];
    const float* bc_v  = (const float*)d_in[5];
    const float* Ws_v  = (const float*)d_in[6];
    const float* bs_v  = (const float*)d_in[7];
    const float* Wd_v  = (const float*)d_in[8];
    const float* bd_v  = (const float*)d_in[9];
    const float* Wc_p  = (const float*)d_in[10];
    const float* bc_p  = (const float*)d_in[11];
    const float* Ws_p  = (const float*)d_in[12];
    const float* bs_p  = (const float*)d_in[13];
    const float* Wd_p  = (const float*)d_in[14];
    const float* bd_p  = (const float*)d_in[15];
    const float* Wsp   = (const float*)d_in[16];
    const float* bsp   = (const float*)d_in[17];
    const float* W1    = (const float*)d_in[18];
    const float* b1    = (const float*)d_in[19];
    const float* W2    = (const float*)d_in[20];
    const float* b2    = (const float*)d_in[21];
    const float* Wa    = (const float*)d_in[22];
    const float* ba    = (const float*)d_in[23];
    const float* Wf    = (const float*)d_in[24];
    const float* bf    = (const float*)d_in[25];
    float* out = (float*)d_out;

    // ws: h_v[B][64] | h_p[B][64] | y30[B][30] | frags (56 x 64 x 16B)
    float* ws  = (float*)d_ws;
    float* h_v = ws;
    float* h_p = ws + (size_t)B_ * 64;
    float* y30 = ws + (size_t)2 * B_ * 64;
    unsigned short* Frag = (unsigned short*)(ws + (size_t)2 * B_ * 64 + (size_t)B_ * 30);

    prep_frags<<<14, 256, 0, stream>>>(W2, Wc_v, Wc_p, W1, bc_v, bc_p, b1,
                                       Ws_v, Wd_v, Ws_p, Wd_p, Wsp, bsp, Wa, ba,
                                       Frag);
    enc_phys_kernel<<<3 * B_, 512, 0, stream>>>(
        S_V, S_P, S_P1, Frag, b2, h_v, h_p, y30);
    head_kernel<<<B_ / HB, 256, 0, stream>>>(
        pairs, h_v, h_p, y30, Frag,
        bs_v, bd_v, bs_p, bd_p, Wf, bf, out);
}